// Round 20
// baseline (148.509 us; speedup 1.0000x reference)
//
#include <hip/hip_runtime.h>

// GraphAttentionWithTypedEdges — MI355X bf16 MFMA implementation, round 20.
// B=2, T=2048, D=1024, H=16, hd=64, E=16384.
//
// Round-20: (a) attn reverted to proven attn12 (r19's setprio was null).
// (b) gemm_out ported to the r14-proven counted-vmcnt pipeline: depth-2
// prefetch, s_waitcnt vmcnt(6) + raw s_barrier (next tile's 6 loads stay in
// flight), frag ds_reads -> regs, lgkmcnt(0) + sched_barrier fence, 2nd
// barrier, STAGE(t+2), MFMAs. Everything else byte-identical to round 16
// (147.4us champion).
//
// ws layout (bytes):
//   [0,8M)    Wt: Wq^T,Wk^T,Wv^T,Wo^T bf16, each [1024][1024]
//   [8M,16M)  Q  bf16 [B,H,T,64] (pre-scaled by 0.125)
//   [16M,24M) K  bf16 [B,H,T,64]
//   [24M,32M) Vt2 bf16 [B,H,32,64,64] (tiled V^T)
//   [32M,40M) attn out bf16 [B,T,H*64]
//   [40M,56M) BiasT fp32 [2048 k][2048 q] (edge slots only: zeroed + added)
// d_out: [0,8M) = x bf16 scratch; [8M,16M) = DT4 bf16 [512][2048][4]
//   (both dead before gemm_out writes).

typedef __attribute__((ext_vector_type(4))) float f32x4;
typedef __attribute__((ext_vector_type(16))) float f32x16;
typedef __bf16 bf16x8 __attribute__((ext_vector_type(8)));

#define DEV static __device__ __forceinline__

DEV ushort f2bf(float f) {
  unsigned u = __float_as_uint(f);
  unsigned r = u + 0x7fffu + ((u >> 16) & 1u);
  return (ushort)(r >> 16);
}

DEV float bf2f(ushort u) { return __uint_as_float((unsigned)u << 16); }

DEV void gl_lds16(const void* g, void* l) {
  __builtin_amdgcn_global_load_lds(
      (const __attribute__((address_space(1))) void*)g,
      (__attribute__((address_space(3))) void*)l, 16, 0, 0);
}

DEV f32x16 mfma32(bf16x8 a, bf16x8 b, f32x16 c) {
  return __builtin_amdgcn_mfma_f32_32x32x16_bf16(a, b, c, 0, 0, 0);
}

DEV unsigned cvtpk(float a, float b) {
  unsigned r;
  asm("v_cvt_pk_bf16_f32 %0, %1, %2" : "=v"(r) : "v"(a), "v"(b));
  return r;
}

// ---------------- conversions (fused) ----------------
// z=0..3: W_z [1024][1024] fp32 -> Wt[z][n][k] bf16 = W_z[k][n]
// z=4: x fp32 -> bf16 (4.19M elements; 1024 virtual blocks x 1024 float4)
__global__ __launch_bounds__(256) void tcvt5_kernel(
    const float* __restrict__ W0, const float* __restrict__ W1,
    const float* __restrict__ W2, const float* __restrict__ W3,
    ushort* __restrict__ Wt, const float* __restrict__ X,
    ushort* __restrict__ Y) {
  const int z = blockIdx.z;
  if (z == 4) {
    const int lb = blockIdx.y * 32 + blockIdx.x;
#pragma unroll
    for (int j = 0; j < 4; ++j) {
      const int i = lb * 1024 + j * 256 + threadIdx.x;
      float4 v = ((const float4*)X)[i];
      ushort4 o;
      o.x = f2bf(v.x); o.y = f2bf(v.y); o.z = f2bf(v.z); o.w = f2bf(v.w);
      ((ushort4*)Y)[i] = o;
    }
    return;
  }
  __shared__ float tile[32][33];
  const float* W = (z == 0) ? W0 : (z == 1) ? W1 : (z == 2) ? W2 : W3;
  ushort* dst = Wt + (size_t)z * 1048576;
  int bx = blockIdx.x * 32, by = blockIdx.y * 32;
  int tx = threadIdx.x & 31, ty = threadIdx.x >> 5;
#pragma unroll
  for (int i = 0; i < 32; i += 8)
    tile[ty + i][tx] = W[(size_t)(by + ty + i) * 1024 + bx + tx];
  __syncthreads();
#pragma unroll
  for (int i = 0; i < 32; i += 8)
    dst[(size_t)(bx + ty + i) * 1024 + by + tx] = f2bf(tile[tx][ty + i]);
}

// ---------------- edge bias (sparse prep) ----------------
// 1) zero only the edge slots of BiasT (duplicates benign)
__global__ __launch_bounds__(256) void zeroE_kernel(
    const int* __restrict__ src, const int* __restrict__ dst,
    float* __restrict__ BiasT, int E) {
  int e = blockIdx.x * 256 + threadIdx.x;
  if (e < E) BiasT[(size_t)dst[e] * 2048 + src[e]] = 0.0f;
}

// 2) scatter-add bias at TRANSPOSED position [dst][src]; the 3 per-type bias
//    scalars are computed redundantly per block (3x1024 dot, trivial).
__global__ __launch_bounds__(256) void scatterT2_kernel(
    const int* __restrict__ src, const int* __restrict__ dst,
    const int* __restrict__ typ, const float* __restrict__ emb,
    const float* __restrict__ tw, float* __restrict__ BiasT, int E) {
  __shared__ float red[256][3];
  const int t = threadIdx.x;
  float p0 = 0.f, p1 = 0.f, p2 = 0.f;
  for (int d = t; d < 1024; d += 256) {
    const float w = tw[d];
    p0 += emb[d] * w;
    p1 += emb[1024 + d] * w;
    p2 += emb[2048 + d] * w;
  }
  red[t][0] = p0; red[t][1] = p1; red[t][2] = p2;
  __syncthreads();
  for (int s = 128; s > 0; s >>= 1) {
    if (t < s) {
      red[t][0] += red[t + s][0];
      red[t][1] += red[t + s][1];
      red[t][2] += red[t + s][2];
    }
    __syncthreads();
  }
  int e = blockIdx.x * 256 + t;
  if (e < E) {
    const float b = red[0][typ[e]];
    atomicAdd(&BiasT[(size_t)dst[e] * 2048 + src[e]], b);
  }
}

// 3) gather-exp only at edge slots into DT4's grouped layout
//    DT4[k>>2][q][k&3] = bf16(exp(BiasT[k][q]) - 1); dup edges write same val.
__global__ __launch_bounds__(256) void dexpE_kernel(
    const int* __restrict__ src, const int* __restrict__ dst,
    const float* __restrict__ BiasT, ushort* __restrict__ DT4, int E) {
  int e = blockIdx.x * 256 + threadIdx.x;
  if (e < E) {
    const int k = dst[e], q = src[e];
    const float b = BiasT[(size_t)k * 2048 + q];
    DT4[((size_t)(k >> 2) * 2048 + q) * 4 + (k & 3)] = f2bf(__expf(b) - 1.0f);
  }
}

// ---------------- GEMMs ----------------
// Fused QKV v3 (r14): 512 threads, double-buffered LDS, counted-vmcnt
// pipeline (depth 2). V^T stored TILED.
__global__ __launch_bounds__(512, 4) void gemm_qkv_kernel(
    const ushort* __restrict__ A, const ushort* __restrict__ Bt3,
    const float* __restrict__ bq, const float* __restrict__ bk,
    const float* __restrict__ bv, ushort* __restrict__ Qo,
    ushort* __restrict__ Ko, ushort* __restrict__ Vt2) {
  __shared__ alignas(16) char Als[2][16384];
  __shared__ alignas(16) char Bls[2][16384];
  const int tid = threadIdx.x, w = tid >> 6, l = tid & 63;
  const int m0 = blockIdx.y * 128, n0 = blockIdx.x * 128;
  const int sr = l >> 2, sg = l & 3;
  const int c = l & 15, gg = l >> 4;
  const int wr = (w >> 1) * 32, wc = (w & 1) * 64;

  f32x4 acc[2][4];
  const f32x4 zf = {0.f, 0.f, 0.f, 0.f};
#pragma unroll
  for (int a2 = 0; a2 < 2; ++a2)
#pragma unroll
    for (int b2 = 0; b2 < 4; ++b2) acc[a2][b2] = zf;

  auto STAGE = [&](int buf, int k0) {
#pragma unroll
    for (int j = 0; j < 2; ++j) {
      const int idx = w * 2 + j, kk = idx >> 3, mb = idx & 7;
      gl_lds16(A + (size_t)(m0 + mb * 16 + sr) * 1024 + k0 + kk * 32 + sg * 8,
               &Als[buf][idx * 1024]);
      gl_lds16(Bt3 + (size_t)(n0 + mb * 16 + sr) * 1024 + k0 + kk * 32 + sg * 8,
               &Bls[buf][idx * 1024]);
    }
  };

  STAGE(0, 0);
  STAGE(1, 64);
  for (int t = 0; t < 16; ++t) {
    const int cur = t & 1;
    if (t < 15) asm volatile("s_waitcnt vmcnt(4)" ::: "memory");
    else        asm volatile("s_waitcnt vmcnt(0)" ::: "memory");
    __builtin_amdgcn_s_barrier();  // tile t visible to all waves

    bf16x8 af[2][2], bfr[2][4];
#pragma unroll
    for (int kk = 0; kk < 2; ++kk) {
#pragma unroll
      for (int f = 0; f < 2; ++f)
        af[kk][f] = *(const bf16x8*)&Als[cur][(kk * 8 + (wr >> 4) + f) * 1024 + c * 64 + gg * 16];
#pragma unroll
      for (int f = 0; f < 4; ++f)
        bfr[kk][f] = *(const bf16x8*)&Bls[cur][(kk * 8 + (wc >> 4) + f) * 1024 + c * 64 + gg * 16];
    }
    asm volatile("s_waitcnt lgkmcnt(0)" ::: "memory");  // frags in regs
    __builtin_amdgcn_sched_barrier(0);                  // rule #18 fence
    __builtin_amdgcn_s_barrier();  // all waves done reading buf[cur]

    if (t < 14) STAGE(cur, (t + 2) * 64);  // overwrite OK; flies under MFMAs

#pragma unroll
    for (int kk = 0; kk < 2; ++kk)
#pragma unroll
      for (int mf = 0; mf < 2; ++mf)
#pragma unroll
        for (int nf = 0; nf < 4; ++nf)
          acc[mf][nf] = __builtin_amdgcn_mfma_f32_16x16x32_bf16(
              af[kk][mf], bfr[kk][nf], acc[mf][nf], 0, 0, 0);
  }

  const int which = n0 >> 10;
  const float scale = (which == 0) ? 0.125f : 1.0f;
  const float* bias = (which == 0) ? bq : (which == 1) ? bk : bv;
#pragma unroll
  for (int mf = 0; mf < 2; ++mf) {
#pragma unroll
    for (int nf = 0; nf < 4; ++nf) {
      const int coln = (n0 & 1023) + wc + nf * 16 + c;
      const float bvv = bias[coln];
      const int h = coln >> 6, d = coln & 63;
#pragma unroll
      for (int i = 0; i < 4; ++i) {
        const int row = m0 + wr + mf * 16 + gg * 4 + i;
        const int b = row >> 11, t = row & 2047;
        const float v = (acc[mf][nf][i] + bvv) * scale;
        const ushort bfv = f2bf(v);
        if (which == 0)
          Qo[((size_t)(b * 16 + h) * 2048 + t) * 64 + d] = bfv;
        else if (which == 1)
          Ko[((size_t)(b * 16 + h) * 2048 + t) * 64 + d] = bfv;
        else  // tiled V^T: [bh][t>>6][d][t&63]
          Vt2[(((size_t)(b * 16 + h) * 32 + (t >> 6)) * 64 + d) * 64 + (t & 63)] = bfv;
      }
    }
  }
}

// Output projection v2: C fp32 [4096][1024] = A(bf16)*Wo + bo. 64x128 tiles,
// grid 512 (XCD swizzle), counted-vmcnt pipeline (depth 2, 6 loads/stage).
__global__ __launch_bounds__(256, 4) void gemm_out_kernel(
    const ushort* __restrict__ A, const ushort* __restrict__ Bt,
    const float* __restrict__ bias, float* __restrict__ outp) {
  __shared__ alignas(16) char Als[2][8192];
  __shared__ alignas(16) char Bls[2][16384];
  const int tid = threadIdx.x, w = tid >> 6, l = tid & 63;
  const int lin = blockIdx.x;
  const int swz = (lin & 7) * 64 + (lin >> 3);  // 512 = 8*64 bijective
  const int m0 = (swz >> 3) * 64, n0 = (swz & 7) * 128;
  const int sr = l >> 2, sg = l & 3;
  const int c = l & 15, gg = l >> 4;
  const int wr = (w & 1) * 32, wc = (w >> 1) * 64;

  f32x4 acc[2][4];
  const f32x4 zf = {0.f, 0.f, 0.f, 0.f};
#pragma unroll
  for (int a2 = 0; a2 < 2; ++a2)
#pragma unroll
    for (int b2 = 0; b2 < 4; ++b2) acc[a2][b2] = zf;

  auto STAGE = [&](int buf, int k0) {
#pragma unroll
    for (int j = 0; j < 2; ++j) {  // A: 8 chunks of 1KB
      const int idx = w * 2 + j, kk = idx >> 2, mb = idx & 3;
      gl_lds16(A + (size_t)(m0 + mb * 16 + sr) * 1024 + k0 + kk * 32 + sg * 8,
               &Als[buf][idx * 1024]);
    }
#pragma unroll
    for (int j = 0; j < 4; ++j) {  // B: 16 chunks
      const int idx = w * 4 + j, kk = idx >> 3, mb = idx & 7;
      gl_lds16(Bt + (size_t)(n0 + mb * 16 + sr) * 1024 + k0 + kk * 32 + sg * 8,
               &Bls[buf][idx * 1024]);
    }
  };

  STAGE(0, 0);
  STAGE(1, 64);
  for (int t = 0; t < 16; ++t) {
    const int cur = t & 1;
    // counted wait: stage(t)'s 6 loads done, stage(t+1)'s 6 stay in flight
    if (t < 15) asm volatile("s_waitcnt vmcnt(6)" ::: "memory");
    else        asm volatile("s_waitcnt vmcnt(0)" ::: "memory");
    __builtin_amdgcn_s_barrier();  // tile t visible to all waves

    bf16x8 af[2][2], bfr[2][4];
#pragma unroll
    for (int kk = 0; kk < 2; ++kk) {
#pragma unroll
      for (int f = 0; f < 2; ++f)
        af[kk][f] = *(const bf16x8*)&Als[cur][(kk * 4 + (wr >> 4) + f) * 1024 + c * 64 + gg * 16];
#pragma unroll
      for (int f = 0; f < 4; ++f)
        bfr[kk][f] = *(const bf16x8*)&Bls[cur][(kk * 8 + (wc >> 4) + f) * 1024 + c * 64 + gg * 16];
    }
    asm volatile("s_waitcnt lgkmcnt(0)" ::: "memory");  // frags in regs
    __builtin_amdgcn_sched_barrier(0);                  // rule #18 fence
    __builtin_amdgcn_s_barrier();  // all waves done reading buf[cur]

    if (t < 14) STAGE(cur, (t + 2) * 64);  // overwrite OK; flies under MFMAs

#pragma unroll
    for (int kk = 0; kk < 2; ++kk)
#pragma unroll
      for (int mf = 0; mf < 2; ++mf)
#pragma unroll
        for (int nf = 0; nf < 4; ++nf)
          acc[mf][nf] = __builtin_amdgcn_mfma_f32_16x16x32_bf16(
              af[kk][mf], bfr[kk][nf], acc[mf][nf], 0, 0, 0);
  }

#pragma unroll
  for (int mf = 0; mf < 2; ++mf) {
#pragma unroll
    for (int nf = 0; nf < 4; ++nf) {
      const int col = n0 + wc + nf * 16 + c;
      const float bvv = bias[col];
#pragma unroll
      for (int i = 0; i < 4; ++i) {
        const int row = m0 + wr + mf * 16 + gg * 4 + i;
        outp[(size_t)row * 1024 + col] = acc[mf][nf][i] + bvv;
      }
    }
  }
}

// ---------------- flash attention v12 (r12/r16 body, unchanged) -------------
// grid 512 (XCD-clustered bh), 512 threads = 2 quads x 4 waves.
// Quad d: keys [d*1024,(d+1)*1024), 16 tiles of 64, private 32KB staging dbuf.
// Wave ww in quad: q cols qt*128 + ww*32. Fixed M=3 softmax (no max chain).
__global__ __launch_bounds__(512, 4) void attn12_kernel(
    const ushort* __restrict__ Q, const ushort* __restrict__ K,
    const ushort* __restrict__ Vt2, const ushort* __restrict__ DT4,
    ushort* __restrict__ Out) {
  __shared__ alignas(16) char smem[65536];
  const int tid = threadIdx.x, w = tid >> 6, l = tid & 63;
  const int c = l & 31, hi = l >> 5;
  const int bid = blockIdx.x;
  const int bh = (bid & 7) * 4 + ((bid >> 3) & 3);  // cluster bh per XCD
  const int qt = bid >> 5;                           // 0..15
  const int bI = bh >> 4, h = bh & 15;
  const int qd = w >> 2, ww = w & 3;                 // quad, wave-in-quad
  const int qw = qt * 128 + ww * 32;                 // this wave's q base
  const int kq = qd * 1024;                          // this quad's key base
  const int qsb = qd * 32768;                        // quad staging base
  const char* Kg = (const char*)(K + (size_t)bh * 2048 * 64);
  const char* Vg = (const char*)(Vt2 + (size_t)bh * 32 * 64 * 64);

  // Q fragments (B-operand of mfma(K,Q)): Qf[ds][j] = Q[qw+c][ds*16+hi*8+j]
  const ushort* Qp = Q + ((size_t)bh * 2048 + qw + c) * 64 + hi * 8;
  bf16x8 Qf[4];
#pragma unroll
  for (int ds = 0; ds < 4; ++ds) Qf[ds] = *(const bf16x8*)(Qp + ds * 16);

  // staging geometry (16B chunk per lane per j; 4 waves/quad cover 8KB tile)
  const int srb = ww * 8 + (l >> 3);                  // row within 32-row half
  const int scol = ((l & 7) << 4) ^ ((l >> 3) << 4);  // pre-swizzled src col
  const int cx = (c & 7) << 4;                        // read-side XOR

  // grouped bias base: DT4[(kg)*2048 + q]*4 ; per-lane q = qw+c, kg varies
  const ushort* Dbase = DT4 + ((size_t)(kq >> 2) * 2048 + qw + c) * 4;

  f32x16 oacc0 = {0,0,0,0,0,0,0,0,0,0,0,0,0,0,0,0};
  f32x16 oacc1 = {0,0,0,0,0,0,0,0,0,0,0,0,0,0,0,0};
  float l_run = 0.f;

  auto STAGE = [&](int buf, int t0) {
#pragma unroll
    for (int j = 0; j < 2; ++j) {
      const int r = j * 32 + srb;
      gl_lds16(Kg + (size_t)(kq + t0 + r) * 128 + scol,
               &smem[qsb + buf * 8192 + j * 4096 + ww * 1024]);
      // tiled V^T: tile (kq+t0)>>6, row r = d, 128B per row
      gl_lds16(Vg + ((size_t)((kq + t0) >> 6) * 64 + r) * 128 + scol,
               &smem[qsb + 16384 + buf * 8192 + j * 4096 + ww * 1024]);
    }
  };

  STAGE(0, 0);
  for (int t = 0; t < 16; ++t) {
    const int cur = t & 1;
    __syncthreads();  // drains vmcnt -> stage(t) visible; prior reads done
    if (t < 15) STAGE(cur ^ 1, (t + 1) * 64);
    const char* KsC = smem + qsb + cur * 8192;
    const char* VsC = smem + qsb + 16384 + cur * 8192;

    // ---- S^T = K * Q over 64 keys (s0: keys 0..31, s1: 32..63) ----
    f32x16 s0 = {0,0,0,0,0,0,0,0,0,0,0,0,0,0,0,0};
    f32x16 s1 = {0,0,0,0,0,0,0,0,0,0,0,0,0,0,0,0};
#pragma unroll
    for (int ds = 0; ds < 4; ++ds) {
      const int col = (ds * 32 + hi * 16) ^ cx;
      bf16x8 k0 = *(const bf16x8*)(KsC + c * 128 + col);
      bf16x8 k1 = *(const bf16x8*)(KsC + (32 + c) * 128 + col);
      s0 = mfma32(k0, Qf[ds], s0);
      s1 = mfma32(k1, Qf[ds], s1);
    }

    // ---- grouped delta loads: 8 x ushort4 (reg quad g needs kg = base+2g+hi,
    //      s1 at +8 groups). dreg[g] pairs with s0 regs 4g..4g+3.  ----
    const ushort* dp = Dbase + (size_t)t * 16 * 8192;  // t*64 keys = 16 groups
    ushort4 dreg[8];
#pragma unroll
    for (int g = 0; g < 4; ++g) {
      dreg[g]     = *(const ushort4*)(dp + (size_t)(2 * g + hi) * 8192);
      dreg[4 + g] = *(const ushort4*)(dp + (size_t)(8 + 2 * g + hi) * 8192);
    }

    // ---- p = exp(s-3) * (1 + delta) ; lane-local l accumulation ----
    float ps[16];
#pragma unroll
    for (int r = 0; r < 16; ++r) {
      const float d0 = bf2f(((const ushort*)&dreg[r >> 2])[r & 3]);
      const float d1 = bf2f(((const ushort*)&dreg[4 + (r >> 2)])[r & 3]);
      float p0 = __expf(s0[r] - 3.0f);
      float p1 = __expf(s1[r] - 3.0f);
      p0 = fmaf(p0, d0, p0);
      p1 = fmaf(p1, d1, p1);
      s0[r] = p0; s1[r] = p1;
      ps[r] = p0 + p1;
    }
#pragma unroll
    for (int off = 8; off; off >>= 1)
#pragma unroll
      for (int r = 0; r < off; ++r) ps[r] += ps[r + off];
    l_run += ps[0];

    // ---- P -> A-frags: cvt_pk pairs + permlane32_swap cross-half ----
    bf16x8 paf[2][2];
#pragma unroll
    for (int kt = 0; kt < 2; ++kt) {
      const f32x16& sv = kt ? s1 : s0;
#pragma unroll
      for (int sl = 0; sl < 2; ++sl) {
        const int rb = sl * 8;
        unsigned u0 = cvtpk(sv[rb + 0], sv[rb + 1]);
        unsigned u1 = cvtpk(sv[rb + 2], sv[rb + 3]);
        unsigned u2 = cvtpk(sv[rb + 4], sv[rb + 5]);
        unsigned u3 = cvtpk(sv[rb + 6], sv[rb + 7]);
        asm("v_permlane32_swap_b32 %0, %1" : "+v"(u0), "+v"(u2));
        asm("v_permlane32_swap_b32 %0, %1" : "+v"(u1), "+v"(u3));
        uint4 uu = {u0, u1, u2, u3};
        paf[kt][sl] = *(bf16x8*)&uu;
      }
    }

    // ---- O += P * V ----
#pragma unroll
    for (int kt = 0; kt < 2; ++kt)
#pragma unroll
      for (int sl = 0; sl < 2; ++sl) {
        const int ks = kt * 2 + sl;
        const int col = (ks * 32 + hi * 16) ^ cx;
        bf16x8 v0 = *(const bf16x8*)(VsC + c * 128 + col);
        bf16x8 v1 = *(const bf16x8*)(VsC + (32 + c) * 128 + col);
        oacc0 = mfma32(paf[kt][sl], v0, oacc0);
        oacc1 = mfma32(paf[kt][sl], v1, oacc1);
      }
  }

  // ---- quad merge (fixed M => plain add of partials) ----
  __syncthreads();  // all staging reads done; LDS reusable
  const float l_tot = l_run + __shfl_xor(l_run, 32);
  float* mb  = (float*)smem + ww * 2048;          // [32 q][64 d] per wave pair
  float* lb  = (float*)(smem + 32768);            // 128 floats
  float* lb2 = (float*)(smem + 32768 + 512);      // 128 floats
  if (qd == 1) {
#pragma unroll
    for (int r = 0; r < 16; ++r) {
      const int qr = (r & 3) + 8 * (r >> 2) + 4 * hi;
      mb[qr * 64 + c] = oacc0[r];
      mb[qr * 64 + 32 + c] = oacc1[r];
    }
    lb[ww * 32 + c] = l_tot;  // dup write across hi halves, benign
  }
  __syncthreads();
  if (qd == 0) {
    const float linv = 1.0f / (l_tot + lb[ww * 32 + c]);
    lb2[ww * 32 + c] = linv;  // same-wave write->read below
    const float* lp = lb2 + ww * 32 + hi * 4;
    f32x4 lv[4];
#pragma unroll
    for (int g2 = 0; g2 < 4; ++g2) lv[g2] = *(const f32x4*)(lp + 8 * g2);
    ushort* Ob = Out + ((size_t)bI * 2048 + qw) * 1024 + h * 64;
#pragma unroll
    for (int r = 0; r < 16; ++r) {
      const int qr = (r & 3) + 8 * (r >> 2) + 4 * hi;
      const float sc = lv[r >> 2][r & 3];
      const float o0 = (oacc0[r] + mb[qr * 64 + c]) * sc;
      const float o1 = (oacc1[r] + mb[qr * 64 + 32 + c]) * sc;
      Ob[(size_t)qr * 1024 + c] = f2bf(o0);
      Ob[(size_t)qr * 1024 + 32 + c] = f2bf(o1);
    }
  }
}

// ---------------- launch ----------------
extern "C" void kernel_launch(void* const* d_in, const int* in_sizes, int n_in,
                              void* d_out, int out_size, void* d_ws, size_t ws_size,
                              hipStream_t stream) {
  (void)n_in; (void)out_size; (void)ws_size;
  const float* x   = (const float*)d_in[0];
  const float* Wq  = (const float*)d_in[1];
  const float* bq  = (const float*)d_in[2];
  const float* Wk  = (const float*)d_in[3];
  const float* bk  = (const float*)d_in[4];
  const float* Wv  = (const float*)d_in[5];
  const float* bv  = (const float*)d_in[6];
  const float* Wo  = (const float*)d_in[7];
  const float* bo  = (const float*)d_in[8];
  const float* emb = (const float*)d_in[9];
  const float* tw  = (const float*)d_in[10];
  const int* esrc  = (const int*)d_in[11];
  const int* edst  = (const int*)d_in[12];
  const int* etyp  = (const int*)d_in[13];
  const int E = in_sizes[11];

  char* ws = (char*)d_ws;
  const size_t MB = 1u << 20;
  ushort* Wtq = (ushort*)(ws + 0 * MB);
  ushort* Wto = (ushort*)(ws + 6 * MB);
  ushort* Wt3 = Wtq;  // contiguous [3072][1024]
  ushort* Qb  = (ushort*)(ws + 8 * MB);
  ushort* Kb  = (ushort*)(ws + 16 * MB);
  ushort* Vt2 = (ushort*)(ws + 24 * MB);
  ushort* Ab  = (ushort*)(ws + 32 * MB);
  float*  BiasT = (float*)(ws + 40 * MB);
  ushort* xbf = (ushort*)d_out;                      // [0,8M) of d_out
  ushort* DT4 = (ushort*)((char*)d_out + 8388608);   // [8M,16M) of d_out

  const int eb = (E + 255) / 256;
  dim3 tg(32, 32, 5);
  tcvt5_kernel<<<tg, 256, 0, stream>>>(Wq, Wk, Wv, Wo, Wtq, x, xbf);
  (void)hipMemsetAsync(DT4, 0, (size_t)2048 * 2048 * 2, stream);
  zeroE_kernel<<<eb, 256, 0, stream>>>(esrc, edst, BiasT, E);
  scatterT2_kernel<<<eb, 256, 0, stream>>>(esrc, edst, etyp, emb, tw, BiasT, E);
  dexpE_kernel<<<eb, 256, 0, stream>>>(esrc, edst, BiasT, DT4, E);

  dim3 gqkv(24, 32);
  gemm_qkv_kernel<<<gqkv, 512, 0, stream>>>(xbf, Wt3, bq, bk, bv, Qb, Kb, Vt2);
  attn12_kernel<<<512, 512, 0, stream>>>(Qb, Kb, Vt2, DT4, Ab);
  gemm_out_kernel<<<512, 256, 0, stream>>>(Ab, Wto, bo, (float*)d_out);
}

// Round 21
// 146.952 us; speedup vs baseline: 1.0106x; 1.0106x over previous
//
#include <hip/hip_runtime.h>

// GraphAttentionWithTypedEdges — MI355X bf16 MFMA implementation, FINAL (=r16).
// B=2, T=2048, D=1024, H=16, hd=64, E=16384.  147.4us (baseline 240.9us).
//
// Final configuration (champion from round 16; r20's gemm_out pipeline port
// reverted — it halved gemm_out occupancy via 48KB LDS and was net-negative):
//  * gemm_qkv: 512 thr, dbuf LDS, counted-vmcnt pipeline (r14, proven −4.5us).
//  * attn12: 2-quad key-split flash attn, fixed-shift softmax, swapped QK^T,
//    in-register P via cvt_pk+permlane32_swap, grouped ushort4 bias deltas
//    (r12, proven −6us), tiled V^T staging (r10).
//  * gemm_out: 64x128 tiles, 1-barrier loop, XCD swizzle (occupancy-optimal).
//  * sparse bias prep: DT4 memset + 3 tiny edge kernels (r16, −2us).
// Refuted & permanently reverted: exp2/C-init fold (r6/r7/r17), fp32 bias
// (r11), attn counted-vmcnt (r15), dreg double-buffer (r18), setprio (r19),
// qkv XCD swizzles (r7/r8), sparse post-correction (r3), key-parity split (r4).
//
// ws layout (bytes):
//   [0,8M)    Wt: Wq^T,Wk^T,Wv^T,Wo^T bf16, each [1024][1024]
//   [8M,16M)  Q  bf16 [B,H,T,64] (pre-scaled by 0.125)
//   [16M,24M) K  bf16 [B,H,T,64]
//   [24M,32M) Vt2 bf16 [B,H,32,64,64] (tiled V^T)
//   [32M,40M) attn out bf16 [B,T,H*64]
//   [40M,56M) BiasT fp32 [2048 k][2048 q] (edge slots only: zeroed + added)
// d_out: [0,8M) = x bf16 scratch; [8M,16M) = DT4 bf16 [512][2048][4]
//   (both dead before gemm_out writes).

typedef __attribute__((ext_vector_type(4))) float f32x4;
typedef __attribute__((ext_vector_type(16))) float f32x16;
typedef __bf16 bf16x8 __attribute__((ext_vector_type(8)));

#define DEV static __device__ __forceinline__

DEV ushort f2bf(float f) {
  unsigned u = __float_as_uint(f);
  unsigned r = u + 0x7fffu + ((u >> 16) & 1u);
  return (ushort)(r >> 16);
}

DEV float bf2f(ushort u) { return __uint_as_float((unsigned)u << 16); }

DEV void gl_lds16(const void* g, void* l) {
  __builtin_amdgcn_global_load_lds(
      (const __attribute__((address_space(1))) void*)g,
      (__attribute__((address_space(3))) void*)l, 16, 0, 0);
}

DEV f32x16 mfma32(bf16x8 a, bf16x8 b, f32x16 c) {
  return __builtin_amdgcn_mfma_f32_32x32x16_bf16(a, b, c, 0, 0, 0);
}

DEV unsigned cvtpk(float a, float b) {
  unsigned r;
  asm("v_cvt_pk_bf16_f32 %0, %1, %2" : "=v"(r) : "v"(a), "v"(b));
  return r;
}

// ---------------- conversions (fused) ----------------
// z=0..3: W_z [1024][1024] fp32 -> Wt[z][n][k] bf16 = W_z[k][n]
// z=4: x fp32 -> bf16 (4.19M elements; 1024 virtual blocks x 1024 float4)
__global__ __launch_bounds__(256) void tcvt5_kernel(
    const float* __restrict__ W0, const float* __restrict__ W1,
    const float* __restrict__ W2, const float* __restrict__ W3,
    ushort* __restrict__ Wt, const float* __restrict__ X,
    ushort* __restrict__ Y) {
  const int z = blockIdx.z;
  if (z == 4) {
    const int lb = blockIdx.y * 32 + blockIdx.x;
#pragma unroll
    for (int j = 0; j < 4; ++j) {
      const int i = lb * 1024 + j * 256 + threadIdx.x;
      float4 v = ((const float4*)X)[i];
      ushort4 o;
      o.x = f2bf(v.x); o.y = f2bf(v.y); o.z = f2bf(v.z); o.w = f2bf(v.w);
      ((ushort4*)Y)[i] = o;
    }
    return;
  }
  __shared__ float tile[32][33];
  const float* W = (z == 0) ? W0 : (z == 1) ? W1 : (z == 2) ? W2 : W3;
  ushort* dst = Wt + (size_t)z * 1048576;
  int bx = blockIdx.x * 32, by = blockIdx.y * 32;
  int tx = threadIdx.x & 31, ty = threadIdx.x >> 5;
#pragma unroll
  for (int i = 0; i < 32; i += 8)
    tile[ty + i][tx] = W[(size_t)(by + ty + i) * 1024 + bx + tx];
  __syncthreads();
#pragma unroll
  for (int i = 0; i < 32; i += 8)
    dst[(size_t)(bx + ty + i) * 1024 + by + tx] = f2bf(tile[tx][ty + i]);
}

// ---------------- edge bias (sparse prep) ----------------
// 1) zero only the edge slots of BiasT (duplicates benign)
__global__ __launch_bounds__(256) void zeroE_kernel(
    const int* __restrict__ src, const int* __restrict__ dst,
    float* __restrict__ BiasT, int E) {
  int e = blockIdx.x * 256 + threadIdx.x;
  if (e < E) BiasT[(size_t)dst[e] * 2048 + src[e]] = 0.0f;
}

// 2) scatter-add bias at TRANSPOSED position [dst][src]; the 3 per-type bias
//    scalars are computed redundantly per block (3x1024 dot, trivial).
__global__ __launch_bounds__(256) void scatterT2_kernel(
    const int* __restrict__ src, const int* __restrict__ dst,
    const int* __restrict__ typ, const float* __restrict__ emb,
    const float* __restrict__ tw, float* __restrict__ BiasT, int E) {
  __shared__ float red[256][3];
  const int t = threadIdx.x;
  float p0 = 0.f, p1 = 0.f, p2 = 0.f;
  for (int d = t; d < 1024; d += 256) {
    const float w = tw[d];
    p0 += emb[d] * w;
    p1 += emb[1024 + d] * w;
    p2 += emb[2048 + d] * w;
  }
  red[t][0] = p0; red[t][1] = p1; red[t][2] = p2;
  __syncthreads();
  for (int s = 128; s > 0; s >>= 1) {
    if (t < s) {
      red[t][0] += red[t + s][0];
      red[t][1] += red[t + s][1];
      red[t][2] += red[t + s][2];
    }
    __syncthreads();
  }
  int e = blockIdx.x * 256 + t;
  if (e < E) {
    const float b = red[0][typ[e]];
    atomicAdd(&BiasT[(size_t)dst[e] * 2048 + src[e]], b);
  }
}

// 3) gather-exp only at edge slots into DT4's grouped layout
//    DT4[k>>2][q][k&3] = bf16(exp(BiasT[k][q]) - 1); dup edges write same val.
__global__ __launch_bounds__(256) void dexpE_kernel(
    const int* __restrict__ src, const int* __restrict__ dst,
    const float* __restrict__ BiasT, ushort* __restrict__ DT4, int E) {
  int e = blockIdx.x * 256 + threadIdx.x;
  if (e < E) {
    const int k = dst[e], q = src[e];
    const float b = BiasT[(size_t)k * 2048 + q];
    DT4[((size_t)(k >> 2) * 2048 + q) * 4 + (k & 3)] = f2bf(__expf(b) - 1.0f);
  }
}

// ---------------- GEMMs ----------------
// Fused QKV v3 (r14): 512 threads, double-buffered LDS, counted-vmcnt
// pipeline (depth 2). V^T stored TILED.
__global__ __launch_bounds__(512, 4) void gemm_qkv_kernel(
    const ushort* __restrict__ A, const ushort* __restrict__ Bt3,
    const float* __restrict__ bq, const float* __restrict__ bk,
    const float* __restrict__ bv, ushort* __restrict__ Qo,
    ushort* __restrict__ Ko, ushort* __restrict__ Vt2) {
  __shared__ alignas(16) char Als[2][16384];
  __shared__ alignas(16) char Bls[2][16384];
  const int tid = threadIdx.x, w = tid >> 6, l = tid & 63;
  const int m0 = blockIdx.y * 128, n0 = blockIdx.x * 128;
  const int sr = l >> 2, sg = l & 3;
  const int c = l & 15, gg = l >> 4;
  const int wr = (w >> 1) * 32, wc = (w & 1) * 64;

  f32x4 acc[2][4];
  const f32x4 zf = {0.f, 0.f, 0.f, 0.f};
#pragma unroll
  for (int a2 = 0; a2 < 2; ++a2)
#pragma unroll
    for (int b2 = 0; b2 < 4; ++b2) acc[a2][b2] = zf;

  auto STAGE = [&](int buf, int k0) {
#pragma unroll
    for (int j = 0; j < 2; ++j) {
      const int idx = w * 2 + j, kk = idx >> 3, mb = idx & 7;
      gl_lds16(A + (size_t)(m0 + mb * 16 + sr) * 1024 + k0 + kk * 32 + sg * 8,
               &Als[buf][idx * 1024]);
      gl_lds16(Bt3 + (size_t)(n0 + mb * 16 + sr) * 1024 + k0 + kk * 32 + sg * 8,
               &Bls[buf][idx * 1024]);
    }
  };

  STAGE(0, 0);
  STAGE(1, 64);
  for (int t = 0; t < 16; ++t) {
    const int cur = t & 1;
    if (t < 15) asm volatile("s_waitcnt vmcnt(4)" ::: "memory");
    else        asm volatile("s_waitcnt vmcnt(0)" ::: "memory");
    __builtin_amdgcn_s_barrier();  // tile t visible to all waves

    bf16x8 af[2][2], bfr[2][4];
#pragma unroll
    for (int kk = 0; kk < 2; ++kk) {
#pragma unroll
      for (int f = 0; f < 2; ++f)
        af[kk][f] = *(const bf16x8*)&Als[cur][(kk * 8 + (wr >> 4) + f) * 1024 + c * 64 + gg * 16];
#pragma unroll
      for (int f = 0; f < 4; ++f)
        bfr[kk][f] = *(const bf16x8*)&Bls[cur][(kk * 8 + (wc >> 4) + f) * 1024 + c * 64 + gg * 16];
    }
    asm volatile("s_waitcnt lgkmcnt(0)" ::: "memory");  // frags in regs
    __builtin_amdgcn_sched_barrier(0);                  // rule #18 fence
    __builtin_amdgcn_s_barrier();  // all waves done reading buf[cur]

    if (t < 14) STAGE(cur, (t + 2) * 64);  // overwrite OK; flies under MFMAs

#pragma unroll
    for (int kk = 0; kk < 2; ++kk)
#pragma unroll
      for (int mf = 0; mf < 2; ++mf)
#pragma unroll
        for (int nf = 0; nf < 4; ++nf)
          acc[mf][nf] = __builtin_amdgcn_mfma_f32_16x16x32_bf16(
              af[kk][mf], bfr[kk][nf], acc[mf][nf], 0, 0, 0);
  }

  const int which = n0 >> 10;
  const float scale = (which == 0) ? 0.125f : 1.0f;
  const float* bias = (which == 0) ? bq : (which == 1) ? bk : bv;
#pragma unroll
  for (int mf = 0; mf < 2; ++mf) {
#pragma unroll
    for (int nf = 0; nf < 4; ++nf) {
      const int coln = (n0 & 1023) + wc + nf * 16 + c;
      const float bvv = bias[coln];
      const int h = coln >> 6, d = coln & 63;
#pragma unroll
      for (int i = 0; i < 4; ++i) {
        const int row = m0 + wr + mf * 16 + gg * 4 + i;
        const int b = row >> 11, t = row & 2047;
        const float v = (acc[mf][nf][i] + bvv) * scale;
        const ushort bfv = f2bf(v);
        if (which == 0)
          Qo[((size_t)(b * 16 + h) * 2048 + t) * 64 + d] = bfv;
        else if (which == 1)
          Ko[((size_t)(b * 16 + h) * 2048 + t) * 64 + d] = bfv;
        else  // tiled V^T: [bh][t>>6][d][t&63]
          Vt2[(((size_t)(b * 16 + h) * 32 + (t >> 6)) * 64 + d) * 64 + (t & 63)] = bfv;
      }
    }
  }
}

// Output projection: C fp32 [4096][1024] = A(bf16)*Wo + bo. 64x128 tiles,
// grid 512 (1-D, XCD swizzle; runs AFTER attn so L2 games are safe).
__global__ __launch_bounds__(256) void gemm_out_kernel(
    const ushort* __restrict__ A, const ushort* __restrict__ Bt,
    const float* __restrict__ bias, float* __restrict__ outp) {
  __shared__ alignas(16) char Als[8192];
  __shared__ alignas(16) char Bls[16384];
  const int tid = threadIdx.x, w = tid >> 6, l = tid & 63;
  const int lin = blockIdx.x;
  const int swz = (lin & 7) * 64 + (lin >> 3);  // 512 = 8*64 bijective
  const int m0 = (swz >> 3) * 64, n0 = (swz & 7) * 128;
  const int sr = l >> 2, sg = l & 3;
  const int c = l & 15, gg = l >> 4;
  const int wr = (w & 1) * 32, wc = (w >> 1) * 64;

  f32x4 acc[2][4];
  const f32x4 zf = {0.f, 0.f, 0.f, 0.f};
#pragma unroll
  for (int a2 = 0; a2 < 2; ++a2)
#pragma unroll
    for (int b2 = 0; b2 < 4; ++b2) acc[a2][b2] = zf;

  for (int k0 = 0; k0 < 1024; k0 += 64) {
#pragma unroll
    for (int j = 0; j < 2; ++j) {  // A: 8 chunks of 1KB
      const int idx = w * 2 + j, kk = idx >> 2, mb = idx & 3;
      gl_lds16(A + (size_t)(m0 + mb * 16 + sr) * 1024 + k0 + kk * 32 + sg * 8,
               &Als[idx * 1024]);
    }
#pragma unroll
    for (int j = 0; j < 4; ++j) {  // B: 16 chunks
      const int idx = w * 4 + j, kk = idx >> 3, mb = idx & 7;
      gl_lds16(Bt + (size_t)(n0 + mb * 16 + sr) * 1024 + k0 + kk * 32 + sg * 8,
               &Bls[idx * 1024]);
    }
    __syncthreads();
#pragma unroll
    for (int kk = 0; kk < 2; ++kk) {
      bf16x8 af[2], bfr[4];
#pragma unroll
      for (int f = 0; f < 2; ++f)
        af[f] = *(const bf16x8*)&Als[(kk * 4 + (wr >> 4) + f) * 1024 + c * 64 + gg * 16];
#pragma unroll
      for (int f = 0; f < 4; ++f)
        bfr[f] = *(const bf16x8*)&Bls[(kk * 8 + (wc >> 4) + f) * 1024 + c * 64 + gg * 16];
#pragma unroll
      for (int mf = 0; mf < 2; ++mf)
#pragma unroll
        for (int nf = 0; nf < 4; ++nf)
          acc[mf][nf] = __builtin_amdgcn_mfma_f32_16x16x32_bf16(
              af[mf], bfr[nf], acc[mf][nf], 0, 0, 0);
    }
    __syncthreads();
  }

#pragma unroll
  for (int mf = 0; mf < 2; ++mf) {
#pragma unroll
    for (int nf = 0; nf < 4; ++nf) {
      const int col = n0 + wc + nf * 16 + c;
      const float bvv = bias[col];
#pragma unroll
      for (int i = 0; i < 4; ++i) {
        const int row = m0 + wr + mf * 16 + gg * 4 + i;
        outp[(size_t)row * 1024 + col] = acc[mf][nf][i] + bvv;
      }
    }
  }
}

// ---------------- flash attention v12 (champion body) -----------------------
// grid 512 (XCD-clustered bh), 512 threads = 2 quads x 4 waves.
// Quad d: keys [d*1024,(d+1)*1024), 16 tiles of 64, private 32KB staging dbuf.
// Wave ww in quad: q cols qt*128 + ww*32. Fixed M=3 softmax (no max chain).
__global__ __launch_bounds__(512, 4) void attn12_kernel(
    const ushort* __restrict__ Q, const ushort* __restrict__ K,
    const ushort* __restrict__ Vt2, const ushort* __restrict__ DT4,
    ushort* __restrict__ Out) {
  __shared__ alignas(16) char smem[65536];
  const int tid = threadIdx.x, w = tid >> 6, l = tid & 63;
  const int c = l & 31, hi = l >> 5;
  const int bid = blockIdx.x;
  const int bh = (bid & 7) * 4 + ((bid >> 3) & 3);  // cluster bh per XCD
  const int qt = bid >> 5;                           // 0..15
  const int bI = bh >> 4, h = bh & 15;
  const int qd = w >> 2, ww = w & 3;                 // quad, wave-in-quad
  const int qw = qt * 128 + ww * 32;                 // this wave's q base
  const int kq = qd * 1024;                          // this quad's key base
  const int qsb = qd * 32768;                        // quad staging base
  const char* Kg = (const char*)(K + (size_t)bh * 2048 * 64);
  const char* Vg = (const char*)(Vt2 + (size_t)bh * 32 * 64 * 64);

  // Q fragments (B-operand of mfma(K,Q)): Qf[ds][j] = Q[qw+c][ds*16+hi*8+j]
  const ushort* Qp = Q + ((size_t)bh * 2048 + qw + c) * 64 + hi * 8;
  bf16x8 Qf[4];
#pragma unroll
  for (int ds = 0; ds < 4; ++ds) Qf[ds] = *(const bf16x8*)(Qp + ds * 16);

  // staging geometry (16B chunk per lane per j; 4 waves/quad cover 8KB tile)
  const int srb = ww * 8 + (l >> 3);                  // row within 32-row half
  const int scol = ((l & 7) << 4) ^ ((l >> 3) << 4);  // pre-swizzled src col
  const int cx = (c & 7) << 4;                        // read-side XOR

  // grouped bias base: DT4[(kg)*2048 + q]*4 ; per-lane q = qw+c, kg varies
  const ushort* Dbase = DT4 + ((size_t)(kq >> 2) * 2048 + qw + c) * 4;

  f32x16 oacc0 = {0,0,0,0,0,0,0,0,0,0,0,0,0,0,0,0};
  f32x16 oacc1 = {0,0,0,0,0,0,0,0,0,0,0,0,0,0,0,0};
  float l_run = 0.f;

  auto STAGE = [&](int buf, int t0) {
#pragma unroll
    for (int j = 0; j < 2; ++j) {
      const int r = j * 32 + srb;
      gl_lds16(Kg + (size_t)(kq + t0 + r) * 128 + scol,
               &smem[qsb + buf * 8192 + j * 4096 + ww * 1024]);
      // tiled V^T: tile (kq+t0)>>6, row r = d, 128B per row
      gl_lds16(Vg + ((size_t)((kq + t0) >> 6) * 64 + r) * 128 + scol,
               &smem[qsb + 16384 + buf * 8192 + j * 4096 + ww * 1024]);
    }
  };

  STAGE(0, 0);
  for (int t = 0; t < 16; ++t) {
    const int cur = t & 1;
    __syncthreads();  // drains vmcnt -> stage(t) visible; prior reads done
    if (t < 15) STAGE(cur ^ 1, (t + 1) * 64);
    const char* KsC = smem + qsb + cur * 8192;
    const char* VsC = smem + qsb + 16384 + cur * 8192;

    // ---- S^T = K * Q over 64 keys (s0: keys 0..31, s1: 32..63) ----
    f32x16 s0 = {0,0,0,0,0,0,0,0,0,0,0,0,0,0,0,0};
    f32x16 s1 = {0,0,0,0,0,0,0,0,0,0,0,0,0,0,0,0};
#pragma unroll
    for (int ds = 0; ds < 4; ++ds) {
      const int col = (ds * 32 + hi * 16) ^ cx;
      bf16x8 k0 = *(const bf16x8*)(KsC + c * 128 + col);
      bf16x8 k1 = *(const bf16x8*)(KsC + (32 + c) * 128 + col);
      s0 = mfma32(k0, Qf[ds], s0);
      s1 = mfma32(k1, Qf[ds], s1);
    }

    // ---- grouped delta loads: 8 x ushort4 (reg quad g needs kg = base+2g+hi,
    //      s1 at +8 groups). dreg[g] pairs with s0 regs 4g..4g+3.  ----
    const ushort* dp = Dbase + (size_t)t * 16 * 8192;  // t*64 keys = 16 groups
    ushort4 dreg[8];
#pragma unroll
    for (int g = 0; g < 4; ++g) {
      dreg[g]     = *(const ushort4*)(dp + (size_t)(2 * g + hi) * 8192);
      dreg[4 + g] = *(const ushort4*)(dp + (size_t)(8 + 2 * g + hi) * 8192);
    }

    // ---- p = exp(s-3) * (1 + delta) ; lane-local l accumulation ----
    float ps[16];
#pragma unroll
    for (int r = 0; r < 16; ++r) {
      const float d0 = bf2f(((const ushort*)&dreg[r >> 2])[r & 3]);
      const float d1 = bf2f(((const ushort*)&dreg[4 + (r >> 2)])[r & 3]);
      float p0 = __expf(s0[r] - 3.0f);
      float p1 = __expf(s1[r] - 3.0f);
      p0 = fmaf(p0, d0, p0);
      p1 = fmaf(p1, d1, p1);
      s0[r] = p0; s1[r] = p1;
      ps[r] = p0 + p1;
    }
#pragma unroll
    for (int off = 8; off; off >>= 1)
#pragma unroll
      for (int r = 0; r < off; ++r) ps[r] += ps[r + off];
    l_run += ps[0];

    // ---- P -> A-frags: cvt_pk pairs + permlane32_swap cross-half ----
    bf16x8 paf[2][2];
#pragma unroll
    for (int kt = 0; kt < 2; ++kt) {
      const f32x16& sv = kt ? s1 : s0;
#pragma unroll
      for (int sl = 0; sl < 2; ++sl) {
        const int rb = sl * 8;
        unsigned u0 = cvtpk(sv[rb + 0], sv[rb + 1]);
        unsigned u1 = cvtpk(sv[rb + 2], sv[rb + 3]);
        unsigned u2 = cvtpk(sv[rb + 4], sv[rb + 5]);
        unsigned u3 = cvtpk(sv[rb + 6], sv[rb + 7]);
        asm("v_permlane32_swap_b32 %0, %1" : "+v"(u0), "+v"(u2));
        asm("v_permlane32_swap_b32 %0, %1" : "+v"(u1), "+v"(u3));
        uint4 uu = {u0, u1, u2, u3};
        paf[kt][sl] = *(bf16x8*)&uu;
      }
    }

    // ---- O += P * V ----
#pragma unroll
    for (int kt = 0; kt < 2; ++kt)
#pragma unroll
      for (int sl = 0; sl < 2; ++sl) {
        const int ks = kt * 2 + sl;
        const int col = (ks * 32 + hi * 16) ^ cx;
        bf16x8 v0 = *(const bf16x8*)(VsC + c * 128 + col);
        bf16x8 v1 = *(const bf16x8*)(VsC + (32 + c) * 128 + col);
        oacc0 = mfma32(paf[kt][sl], v0, oacc0);
        oacc1 = mfma32(paf[kt][sl], v1, oacc1);
      }
  }

  // ---- quad merge (fixed M => plain add of partials) ----
  __syncthreads();  // all staging reads done; LDS reusable
  const float l_tot = l_run + __shfl_xor(l_run, 32);
  float* mb  = (float*)smem + ww * 2048;          // [32 q][64 d] per wave pair
  float* lb  = (float*)(smem + 32768);            // 128 floats
  float* lb2 = (float*)(smem + 32768 + 512);      // 128 floats
  if (qd == 1) {
#pragma unroll
    for (int r = 0; r < 16; ++r) {
      const int qr = (r & 3) + 8 * (r >> 2) + 4 * hi;
      mb[qr * 64 + c] = oacc0[r];
      mb[qr * 64 + 32 + c] = oacc1[r];
    }
    lb[ww * 32 + c] = l_tot;  // dup write across hi halves, benign
  }
  __syncthreads();
  if (qd == 0) {
    const float linv = 1.0f / (l_tot + lb[ww * 32 + c]);
    lb2[ww * 32 + c] = linv;  // same-wave write->read below
    const float* lp = lb2 + ww * 32 + hi * 4;
    f32x4 lv[4];
#pragma unroll
    for (int g2 = 0; g2 < 4; ++g2) lv[g2] = *(const f32x4*)(lp + 8 * g2);
    ushort* Ob = Out + ((size_t)bI * 2048 + qw) * 1024 + h * 64;
#pragma unroll
    for (int r = 0; r < 16; ++r) {
      const int qr = (r & 3) + 8 * (r >> 2) + 4 * hi;
      const float sc = lv[r >> 2][r & 3];
      const float o0 = (oacc0[r] + mb[qr * 64 + c]) * sc;
      const float o1 = (oacc1[r] + mb[qr * 64 + 32 + c]) * sc;
      Ob[(size_t)qr * 1024 + c] = f2bf(o0);
      Ob[(size_t)qr * 1024 + 32 + c] = f2bf(o1);
    }
  }
}

// ---------------- launch ----------------
extern "C" void kernel_launch(void* const* d_in, const int* in_sizes, int n_in,
                              void* d_out, int out_size, void* d_ws, size_t ws_size,
                              hipStream_t stream) {
  (void)n_in; (void)out_size; (void)ws_size;
  const float* x   = (const float*)d_in[0];
  const float* Wq  = (const float*)d_in[1];
  const float* bq  = (const float*)d_in[2];
  const float* Wk  = (const float*)d_in[3];
  const float* bk  = (const float*)d_in[4];
  const float* Wv  = (const float*)d_in[5];
  const float* bv  = (const float*)d_in[6];
  const float* Wo  = (const float*)d_in[7];
  const float* bo  = (const float*)d_in[8];
  const float* emb = (const float*)d_in[9];
  const float* tw  = (const float*)d_in[10];
  const int* esrc  = (const int*)d_in[11];
  const int* edst  = (const int*)d_in[12];
  const int* etyp  = (const int*)d_in[13];
  const int E = in_sizes[11];

  char* ws = (char*)d_ws;
  const size_t MB = 1u << 20;
  ushort* Wtq = (ushort*)(ws + 0 * MB);
  ushort* Wto = (ushort*)(ws + 6 * MB);
  ushort* Wt3 = Wtq;  // contiguous [3072][1024]
  ushort* Qb  = (ushort*)(ws + 8 * MB);
  ushort* Kb  = (ushort*)(ws + 16 * MB);
  ushort* Vt2 = (ushort*)(ws + 24 * MB);
  ushort* Ab  = (ushort*)(ws + 32 * MB);
  float*  BiasT = (float*)(ws + 40 * MB);
  ushort* xbf = (ushort*)d_out;                      // [0,8M) of d_out
  ushort* DT4 = (ushort*)((char*)d_out + 8388608);   // [8M,16M) of d_out

  const int eb = (E + 255) / 256;
  dim3 tg(32, 32, 5);
  tcvt5_kernel<<<tg, 256, 0, stream>>>(Wq, Wk, Wv, Wo, Wtq, x, xbf);
  (void)hipMemsetAsync(DT4, 0, (size_t)2048 * 2048 * 2, stream);
  zeroE_kernel<<<eb, 256, 0, stream>>>(esrc, edst, BiasT, E);
  scatterT2_kernel<<<eb, 256, 0, stream>>>(esrc, edst, etyp, emb, tw, BiasT, E);
  dexpE_kernel<<<eb, 256, 0, stream>>>(esrc, edst, BiasT, DT4, E);

  dim3 gqkv(24, 32);
  gemm_qkv_kernel<<<gqkv, 512, 0, stream>>>(xbf, Wt3, bq, bk, bv, Qb, Kb, Vt2);
  attn12_kernel<<<512, 512, 0, stream>>>(Qb, Kb, Vt2, DT4, Ab);
  gemm_out_kernel<<<512, 256, 0, stream>>>(Ab, Wto, bo, (float*)d_out);
}